// Round 8
// baseline (80.697 us; speedup 1.0000x reference)
//
#include <hip/hip_runtime.h>
#include <math.h>

#define D 256
#define Q 256
#define I 2048
#define STRIDE 264   // shorts per LDS row: 256 + 8 pad -> uniform bank spread

typedef __attribute__((ext_vector_type(8))) short short8;
typedef __attribute__((ext_vector_type(4))) float floatx4;

__device__ __forceinline__ float grp16_sum(float v) {
    v += __shfl_xor(v, 1, 64);
    v += __shfl_xor(v, 2, 64);
    v += __shfl_xor(v, 4, 64);
    v += __shfl_xor(v, 8, 64);
    return v;
}

__device__ __forceinline__ float sigmoidf_(float x) {
    return 1.0f / (1.0f + expf(-x));
}

// fp32 -> bf16 round-to-nearest-even
__device__ __forceinline__ unsigned short f2bf(float f) {
    unsigned u = __float_as_uint(f);
    u += 0x7FFFu + ((u >> 16) & 1u);
    return (unsigned short)(u >> 16);
}

// Fully fused: each block recomputes the prep it needs (64 queries, 32 gallery
// rows), stages bf16 MFMA operands in LDS, one barrier, then 48 MFMAs/wave.
// grid = (Q/64, I/32); block = 256 (4 waves); 1 block/CU (135 KB LDS).
// Lane split for prep: jq = lane>>4 (one of 4 rows), s = lane&15 (d = 16s..16s+15).
__global__ void __launch_bounds__(256, 1)
fused_scores(const float* __restrict__ qf,
             const float* __restrict__ qif,
             const float* __restrict__ gal,
             const float* __restrict__ gamma,
             const float* __restrict__ beta,
             const float* __restrict__ mean,
             const float* __restrict__ var,
             float* __restrict__ out) {
    __shared__ unsigned short sP[64 * STRIDE];
    __shared__ unsigned short sW[64 * STRIDE];
    __shared__ unsigned short sV[64 * STRIDE];
    __shared__ unsigned short sY[32 * STRIDE];
    __shared__ unsigned short sY2[32 * STRIDE];
    __shared__ float ssq[64];

    const int t = threadIdx.x, wv = t >> 6, l = t & 63;
    const int jq = l >> 4, s = l & 15;
    const int q0 = blockIdx.x * 64, i0 = blockIdx.y * 32;

    // ---- bn constants for this lane's d = 16s..16s+15 (shared by all rows) ----
    const float4* ga4 = (const float4*)gamma;
    const float4* be4 = (const float4*)beta;
    const float4* me4 = (const float4*)mean;
    const float4* va4 = (const float4*)var;
    float isv[16], cv[16];
#pragma unroll
    for (int m = 0; m < 4; m++) {
        float4 gm = ga4[s * 4 + m], vr = va4[s * 4 + m];
        float4 bt = be4[s * 4 + m], mn = me4[s * 4 + m];
        isv[4 * m + 0] = gm.x * rsqrtf(vr.x + 1e-5f);
        isv[4 * m + 1] = gm.y * rsqrtf(vr.y + 1e-5f);
        isv[4 * m + 2] = gm.z * rsqrtf(vr.z + 1e-5f);
        isv[4 * m + 3] = gm.w * rsqrtf(vr.w + 1e-5f);
        cv[4 * m + 0] = bt.x - mn.x * isv[4 * m + 0];
        cv[4 * m + 1] = bt.y - mn.y * isv[4 * m + 1];
        cv[4 * m + 2] = bt.z - mn.z * isv[4 * m + 2];
        cv[4 * m + 3] = bt.w - mn.w * isv[4 * m + 3];
    }
    float ccl = 0.f;
#pragma unroll
    for (int e = 0; e < 16; e++) ccl += cv[e] * cv[e];
    const float cc = grp16_sum(ccl);   // sum over all 256 d

    // ---- gallery: 8 rows per wave (2 rounds x 4 rows), loads issued first ----
    const float4* g4 = (const float4*)gal;
    float gx[2][16];
#pragma unroll
    for (int rr = 0; rr < 2; rr++) {
        const int i = i0 + wv * 8 + rr * 4 + jq;
#pragma unroll
        for (int m = 0; m < 4; m++) {
            float4 r = g4[(size_t)i * 64 + s * 4 + m];
            gx[rr][4 * m + 0] = r.x; gx[rr][4 * m + 1] = r.y;
            gx[rr][4 * m + 2] = r.z; gx[rr][4 * m + 3] = r.w;
        }
    }
#pragma unroll
    for (int rr = 0; rr < 2; rr++) {
        const int iloc = wv * 8 + rr * 4 + jq;
        float nn = 0.f;
#pragma unroll
        for (int e = 0; e < 16; e++) nn += gx[rr][e] * gx[rr][e];
        nn = grp16_sum(nn);
        const float inv = 1.0f / fmaxf(sqrtf(nn), 1e-12f);
        unsigned short uy[16], uy2[16];
#pragma unroll
        for (int e = 0; e < 16; e++) {
            float y = gx[rr][e] * inv;
            uy[e]  = f2bf(y);
            uy2[e] = f2bf(y * y);
        }
        *(short8*)&sY [iloc * STRIDE + s * 16]     = *(short8*)&uy[0];
        *(short8*)&sY [iloc * STRIDE + s * 16 + 8] = *(short8*)&uy[8];
        *(short8*)&sY2[iloc * STRIDE + s * 16]     = *(short8*)&uy2[0];
        *(short8*)&sY2[iloc * STRIDE + s * 16 + 8] = *(short8*)&uy2[8];
    }

    // ---- queries: 16 per wave (4 rounds x 4), all loads issued first ----
    const float4* qf4 = (const float4*)qf;
    const float4* qi4 = (const float4*)qif;
    float qx[4][16], qy[4][16];
#pragma unroll
    for (int r = 0; r < 4; r++) {
        const int q = q0 + wv * 16 + r * 4 + jq;
#pragma unroll
        for (int m = 0; m < 4; m++) {
            float4 a = qf4[(size_t)q * 64 + s * 4 + m];
            float4 b = qi4[(size_t)q * 64 + s * 4 + m];
            qx[r][4 * m + 0] = a.x; qx[r][4 * m + 1] = a.y;
            qx[r][4 * m + 2] = a.z; qx[r][4 * m + 3] = a.w;
            qy[r][4 * m + 0] = b.x; qy[r][4 * m + 1] = b.y;
            qy[r][4 * m + 2] = b.z; qy[r][4 * m + 3] = b.w;
        }
    }
#pragma unroll
    for (int r = 0; r < 4; r++) {
        const int qloc = wv * 16 + r * 4 + jq;
        float nx = 0.f, ny = 0.f;
#pragma unroll
        for (int e = 0; e < 16; e++) {
            nx += qx[r][e] * qx[r][e];
            ny += qy[r][e] * qy[r][e];
        }
        nx = grp16_sum(nx);
        ny = grp16_sum(ny);
        const float inx = 1.0f / fmaxf(sqrtf(nx), 1e-12f);
        const float iny = 1.0f / fmaxf(sqrtf(ny), 1e-12f);

        float av[16], fv[16];
        float nf = 0.f;
#pragma unroll
        for (int e = 0; e < 16; e++) {
            float gate = sigmoidf_(qx[r][e] * inx * 5.0f);
            av[e] = gate * isv[e];
            fv[e] = qy[r][e] * iny * av[e] + cv[e];
            nf += fv[e] * fv[e];
        }
        nf = grp16_sum(nf);
        const float inf_ = 1.0f / fmaxf(sqrtf(nf), 1e-12f);

        unsigned short up[16], uw[16], uv[16];
        float usum = 0.f;
#pragma unroll
        for (int e = 0; e < 16; e++) {
            float u = fv[e] * inf_;
            up[e] = f2bf(u * av[e]);
            uw[e] = f2bf(av[e] * av[e]);
            uv[e] = f2bf(2.0f * av[e] * cv[e]);
            usum += u * cv[e];
        }
        usum = grp16_sum(usum);
        if (s == 0) ssq[qloc] = usum;

        *(short8*)&sP[qloc * STRIDE + s * 16]     = *(short8*)&up[0];
        *(short8*)&sP[qloc * STRIDE + s * 16 + 8] = *(short8*)&up[8];
        *(short8*)&sW[qloc * STRIDE + s * 16]     = *(short8*)&uw[0];
        *(short8*)&sW[qloc * STRIDE + s * 16 + 8] = *(short8*)&uw[8];
        *(short8*)&sV[qloc * STRIDE + s * 16]     = *(short8*)&uv[0];
        *(short8*)&sV[qloc * STRIDE + s * 16 + 8] = *(short8*)&uv[8];
    }

    __syncthreads();

    // ---- MFMA: wave = 16 queries x 32 items, K=256 ----
    const int lm = l & 15, quad = l >> 4, koff = quad * 8;
    short8 bp[8], bw[8], bv[8];
#pragma unroll
    for (int ks = 0; ks < 8; ks++) {
        const int o = (wv * 16 + lm) * STRIDE + ks * 32 + koff;
        bp[ks] = *(const short8*)&sP[o];
        bw[ks] = *(const short8*)&sW[o];
        bv[ks] = *(const short8*)&sV[o];
    }
    const float sqv = ssq[wv * 16 + lm];
    const int qr = q0 + wv * 16 + lm;

#pragma unroll
    for (int it = 0; it < 2; it++) {
        floatx4 acc1 = {0.f, 0.f, 0.f, 0.f};
        floatx4 acc2 = {0.f, 0.f, 0.f, 0.f};
#pragma unroll
        for (int ks = 0; ks < 8; ks++) {
            const int o = (it * 16 + lm) * STRIDE + ks * 32 + koff;
            short8 ay  = *(const short8*)&sY[o];
            short8 ay2 = *(const short8*)&sY2[o];
            acc1 = __builtin_amdgcn_mfma_f32_16x16x32_bf16(ay,  bp[ks], acc1, 0, 0, 0);
            acc2 = __builtin_amdgcn_mfma_f32_16x16x32_bf16(ay2, bw[ks], acc2, 0, 0, 0);
            acc2 = __builtin_amdgcn_mfma_f32_16x16x32_bf16(ay,  bv[ks], acc2, 0, 0, 0);
        }
        float4 o4;
        float* po = &o4.x;
#pragma unroll
        for (int rr = 0; rr < 4; rr++) {
            float nrm = fmaxf(sqrtf(fmaxf(acc2[rr] + cc, 0.f)), 1e-12f);
            po[rr] = sigmoidf_((acc1[rr] + sqv) / nrm);
        }
        *(float4*)&out[(size_t)qr * I + i0 + it * 16 + quad * 4] = o4;
    }
}

extern "C" void kernel_launch(void* const* d_in, const int* in_sizes, int n_in,
                              void* d_out, int out_size, void* d_ws, size_t ws_size,
                              hipStream_t stream) {
    const float* qf    = (const float*)d_in[0]; // [Q,D]
    const float* qif   = (const float*)d_in[1]; // [Q,D]
    const float* gal   = (const float*)d_in[2]; // [I,D]
    const float* gamma = (const float*)d_in[3];
    const float* beta  = (const float*)d_in[4];
    const float* mean  = (const float*)d_in[5];
    const float* var   = (const float*)d_in[6];
    float* out = (float*)d_out;                 // [Q,I]

    fused_scores<<<dim3(Q / 64, I / 32), 256, 0, stream>>>(
        qf, qif, gal, gamma, beta, mean, var, out);
}

// Round 9
// 75.611 us; speedup vs baseline: 1.0673x; 1.0673x over previous
//
#include <hip/hip_runtime.h>
#include <math.h>

#define D 256
#define Q 256
#define I 2048
#define STRIDE 264   // shorts per LDS row: 256 + 8 pad -> uniform bank spread

typedef __attribute__((ext_vector_type(8))) short short8;
typedef __attribute__((ext_vector_type(4))) float floatx4;

__device__ __forceinline__ float wave_sum(float v) {
#pragma unroll
    for (int off = 1; off < 64; off <<= 1)
        v += __shfl_xor(v, off, 64);
    return v;
}

__device__ __forceinline__ float grp16_sum(float v) {
    v += __shfl_xor(v, 1, 64);
    v += __shfl_xor(v, 2, 64);
    v += __shfl_xor(v, 4, 64);
    v += __shfl_xor(v, 8, 64);
    return v;
}

__device__ __forceinline__ float sigmoidf_(float x) {
    return 1.0f / (1.0f + expf(-x));
}

// fp32 -> bf16 round-to-nearest-even
__device__ __forceinline__ unsigned short f2bf(float f) {
    unsigned u = __float_as_uint(f);
    u += 0x7FFFu + ((u >> 16) & 1u);
    return (unsigned short)(u >> 16);
}

// Query prep only (transcendental-heavy -> computed exactly once).
// 64 blocks x 256 threads; one query per wave; lane holds d = 4l..4l+3.
// Writes bf16 P/W/V row-major [q][d] + fp32 sq[q], cc.
__global__ void __launch_bounds__(256)
query_prep(const float* __restrict__ qf,
           const float* __restrict__ qif,
           const float* __restrict__ gamma,
           const float* __restrict__ beta,
           const float* __restrict__ mean,
           const float* __restrict__ var,
           unsigned short* __restrict__ PB,
           unsigned short* __restrict__ WB,
           unsigned short* __restrict__ VB,
           float* __restrict__ sq,
           float* __restrict__ ccp) {
    const int t = threadIdx.x;
    const int wv = t >> 6, l = t & 63;
    const int q = blockIdx.x * 4 + wv;
    const float4* qf4  = (const float4*)qf;
    const float4* qif4 = (const float4*)qif;
    const float4* ga4  = (const float4*)gamma;
    const float4* be4  = (const float4*)beta;
    const float4* me4  = (const float4*)mean;
    const float4* va4  = (const float4*)var;

    float4 x = qf4[(size_t)q * 64 + l];
    float nx = wave_sum(x.x * x.x + x.y * x.y + x.z * x.z + x.w * x.w);
    float inx = 1.0f / fmaxf(sqrtf(nx), 1e-12f);
    float g0 = sigmoidf_(x.x * inx * 5.0f);
    float g1 = sigmoidf_(x.y * inx * 5.0f);
    float g2 = sigmoidf_(x.z * inx * 5.0f);
    float g3 = sigmoidf_(x.w * inx * 5.0f);

    float4 y = qif4[(size_t)q * 64 + l];
    float ny = wave_sum(y.x * y.x + y.y * y.y + y.z * y.z + y.w * y.w);
    float iny = 1.0f / fmaxf(sqrtf(ny), 1e-12f);

    float4 gm = ga4[l], bt = be4[l], mn = me4[l], vr = va4[l];
    float is0 = gm.x * rsqrtf(vr.x + 1e-5f);
    float is1 = gm.y * rsqrtf(vr.y + 1e-5f);
    float is2 = gm.z * rsqrtf(vr.z + 1e-5f);
    float is3 = gm.w * rsqrtf(vr.w + 1e-5f);
    float c0 = bt.x - mn.x * is0;
    float c1 = bt.y - mn.y * is1;
    float c2 = bt.z - mn.z * is2;
    float c3 = bt.w - mn.w * is3;
    float a0 = g0 * is0, a1 = g1 * is1, a2 = g2 * is2, a3 = g3 * is3;

    float f0 = y.x * iny * a0 + c0;
    float f1 = y.y * iny * a1 + c1;
    float f2 = y.z * iny * a2 + c2;
    float f3 = y.w * iny * a3 + c3;
    float nf = wave_sum(f0 * f0 + f1 * f1 + f2 * f2 + f3 * f3);
    float inf_ = 1.0f / fmaxf(sqrtf(nf), 1e-12f);
    float u0 = f0 * inf_, u1 = f1 * inf_, u2 = f2 * inf_, u3 = f3 * inf_;

    *(ushort4*)&PB[(size_t)q * D + 4 * l] =
        make_ushort4(f2bf(u0 * a0), f2bf(u1 * a1), f2bf(u2 * a2), f2bf(u3 * a3));
    *(ushort4*)&WB[(size_t)q * D + 4 * l] =
        make_ushort4(f2bf(a0 * a0), f2bf(a1 * a1), f2bf(a2 * a2), f2bf(a3 * a3));
    *(ushort4*)&VB[(size_t)q * D + 4 * l] =
        make_ushort4(f2bf(2.0f * a0 * c0), f2bf(2.0f * a1 * c1),
                     f2bf(2.0f * a2 * c2), f2bf(2.0f * a3 * c3));

    float s = wave_sum(u0 * c0 + u1 * c1 + u2 * c2 + u3 * c3);
    if (l == 0) sq[q] = s;

    if (q == 0) {
        float ccs = wave_sum(c0 * c0 + c1 * c1 + c2 * c2 + c3 * c3);
        if (l == 0) *ccp = ccs;
    }
}

// Main: gallery normalize fused in-block (cheap, 4x redundant), then MFMA.
//   acc1[i,q] = sum_k Y[i,k]  * P[q,k]
//   acc2[i,q] = sum_k Y2[i,k] * W[q,k] + Y[i,k] * V[q,k]
// grid = (Q/64, I/32); block = 256 (4 waves). Wave: 16 q x 32 i, K=256.
// A-frags (Y/Y2) from LDS (33 KB); B-frags (P/W/V) hoisted from global bf16.
__global__ void __launch_bounds__(256)
main_scores(const float* __restrict__ gal,
            const unsigned short* __restrict__ PB,
            const unsigned short* __restrict__ WB,
            const unsigned short* __restrict__ VB,
            const float* __restrict__ sq,
            const float* __restrict__ ccp,
            float* __restrict__ out) {
    __shared__ unsigned short sY[32 * STRIDE];
    __shared__ unsigned short sY2[32 * STRIDE];

    const int t = threadIdx.x, wv = t >> 6, l = t & 63;
    const int jq = l >> 4, s = l & 15;
    const int q0 = blockIdx.x * 64, i0 = blockIdx.y * 32;

    // ---- gallery: 8 rows per wave (2 rounds x 4 rows); 16 lanes per row ----
    const float4* g4 = (const float4*)gal;
    float gx[2][16];
#pragma unroll
    for (int rr = 0; rr < 2; rr++) {
        const int i = i0 + wv * 8 + rr * 4 + jq;
#pragma unroll
        for (int m = 0; m < 4; m++) {
            float4 r = g4[(size_t)i * 64 + s * 4 + m];
            gx[rr][4 * m + 0] = r.x; gx[rr][4 * m + 1] = r.y;
            gx[rr][4 * m + 2] = r.z; gx[rr][4 * m + 3] = r.w;
        }
    }
#pragma unroll
    for (int rr = 0; rr < 2; rr++) {
        const int iloc = wv * 8 + rr * 4 + jq;
        float nn = 0.f;
#pragma unroll
        for (int e = 0; e < 16; e++) nn += gx[rr][e] * gx[rr][e];
        nn = grp16_sum(nn);
        const float inv = 1.0f / fmaxf(sqrtf(nn), 1e-12f);
        unsigned short uy[16], uy2[16];
#pragma unroll
        for (int e = 0; e < 16; e++) {
            float yv = gx[rr][e] * inv;
            uy[e]  = f2bf(yv);
            uy2[e] = f2bf(yv * yv);
        }
        *(short8*)&sY [iloc * STRIDE + s * 16]     = *(short8*)&uy[0];
        *(short8*)&sY [iloc * STRIDE + s * 16 + 8] = *(short8*)&uy[8];
        *(short8*)&sY2[iloc * STRIDE + s * 16]     = *(short8*)&uy2[0];
        *(short8*)&sY2[iloc * STRIDE + s * 16 + 8] = *(short8*)&uy2[8];
    }

    // ---- B-frags: full K=256 hoisted from global (overlaps gallery prep) ----
    const int lm = l & 15, quad = l >> 4, koff = quad * 8;
    const int qr = q0 + wv * 16 + lm;
    short8 bp[8], bw[8], bv[8];
#pragma unroll
    for (int ks = 0; ks < 8; ks++) {
        const size_t o = (size_t)qr * D + ks * 32 + koff;
        bp[ks] = *(const short8*)&PB[o];
        bw[ks] = *(const short8*)&WB[o];
        bv[ks] = *(const short8*)&VB[o];
    }
    const float sqv = sq[qr];
    const float ccv = *ccp;

    __syncthreads();

    // ---- MFMA: wave = 16 queries x 32 items, K=256 ----
#pragma unroll
    for (int it = 0; it < 2; it++) {
        floatx4 acc1 = {0.f, 0.f, 0.f, 0.f};
        floatx4 acc2 = {0.f, 0.f, 0.f, 0.f};
#pragma unroll
        for (int ks = 0; ks < 8; ks++) {
            const int o = (it * 16 + lm) * STRIDE + ks * 32 + koff;
            short8 ay  = *(const short8*)&sY[o];
            short8 ay2 = *(const short8*)&sY2[o];
            acc1 = __builtin_amdgcn_mfma_f32_16x16x32_bf16(ay,  bp[ks], acc1, 0, 0, 0);
            acc2 = __builtin_amdgcn_mfma_f32_16x16x32_bf16(ay2, bw[ks], acc2, 0, 0, 0);
            acc2 = __builtin_amdgcn_mfma_f32_16x16x32_bf16(ay,  bv[ks], acc2, 0, 0, 0);
        }
        float4 o4;
        float* po = &o4.x;
#pragma unroll
        for (int rr = 0; rr < 4; rr++) {
            float nrm = fmaxf(sqrtf(fmaxf(acc2[rr] + ccv, 0.f)), 1e-12f);
            po[rr] = sigmoidf_((acc1[rr] + sqv) / nrm);
        }
        *(float4*)&out[(size_t)qr * I + i0 + it * 16 + quad * 4] = o4;
    }
}

extern "C" void kernel_launch(void* const* d_in, const int* in_sizes, int n_in,
                              void* d_out, int out_size, void* d_ws, size_t ws_size,
                              hipStream_t stream) {
    const float* qf    = (const float*)d_in[0]; // [Q,D]
    const float* qif   = (const float*)d_in[1]; // [Q,D]
    const float* gal   = (const float*)d_in[2]; // [I,D]
    const float* gamma = (const float*)d_in[3];
    const float* beta  = (const float*)d_in[4];
    const float* mean  = (const float*)d_in[5];
    const float* var   = (const float*)d_in[6];
    float* out = (float*)d_out;                 // [Q,I]

    char* base = (char*)d_ws;
    float* sq = (float*)base;                               // Q floats
    float* cc = (float*)(base + 1024);                      // 1 float
    unsigned short* PB = (unsigned short*)(base + 2048);    // Q*D bf16
    unsigned short* WB = PB + (size_t)Q * D;
    unsigned short* VB = WB + (size_t)Q * D;

    query_prep<<<Q / 4, 256, 0, stream>>>(qf, qif, gamma, beta, mean, var,
                                          PB, WB, VB, sq, cc);
    main_scores<<<dim3(Q / 64, I / 32), 256, 0, stream>>>(gal, PB, WB, VB,
                                                          sq, cc, out);
}